// Round 5
// baseline (63.189 us; speedup 1.0000x reference)
//
#include <hip/hip_runtime.h>
#include <hip/hip_bf16.h>

// out[b,n,u] = sum_t x[b,n,t] * W_eff[u,t] + b_eff[u]
//   W_eff = Ws + (Wt - Ws) @ A   (A = causal window-mean, window 25)
// M = 16384, T = 720, Kp = 736 (23*32), W rows padded to 768 (zero-filled).
// GEMM: 128x128 tile, 4 waves (2x2), BK=32, DOUBLE-buffered LDS, T3-minimal
// pipeline: issue t+1 stage loads -> compute t -> ds_write t+1 -> ONE barrier.
// Linear LDS everywhere. m0/n0 block-level; wr*64/wc*64 in frags AND epilogue.

#define Tdim  720
#define KP    736
#define WROWS 768
#define NK    23
#define NBLK  6      // n-tiles (720 -> 6 x 128)

using bf16x8 = __attribute__((ext_vector_type(8))) __bf16;
using f32x4  = __attribute__((ext_vector_type(4))) float;

typedef const __attribute__((address_space(1))) void* gas_ptr;
typedef __attribute__((address_space(3))) void* las_ptr;

__global__ void fold_w_kernel(const float* __restrict__ tw,
                              const float* __restrict__ tb,
                              const float* __restrict__ sw,
                              const float* __restrict__ sb,
                              __bf16* __restrict__ Wb,
                              float* __restrict__ beff) {
  int idx = blockIdx.x * 256 + threadIdx.x;
  if (idx >= WROWS * KP) return;
  int u = idx / KP;
  int i = idx - u * KP;
  float w = 0.0f;
  if (u < Tdim && i < Tdim) {
    const float* twr = tw + (size_t)u * Tdim;
    const float* swr = sw + (size_t)u * Tdim;
    int tend = (i + 25 < Tdim) ? (i + 25) : Tdim;
    float acc = 0.0f;
    if (i >= 24) {
      #pragma unroll 5
      for (int t = i; t < tend; ++t) acc += twr[t] - swr[t];
      acc *= 0.04f;
    } else {
      for (int t = i; t < tend; ++t) {
        float c = (t >= 24) ? 0.04f : 1.0f / (float)(t + 1);
        acc += (twr[t] - swr[t]) * c;
      }
    }
    w = swr[i] + acc;
  }
  Wb[idx] = (__bf16)w;
  if (i == 0 && u < Tdim) beff[u] = tb[u] + sb[u];
}

__global__ __launch_bounds__(256, 3)
void dlinear_gemm(const float* __restrict__ x,
                  const __bf16* __restrict__ Wb,
                  const float* __restrict__ beff,
                  float* __restrict__ out, int Mtotal) {
  __shared__ __bf16 As[2][128 * 32];
  __shared__ __bf16 Bs[2][128 * 32];

  const int tid  = threadIdx.x;
  const int lane = tid & 63;
  const int wid  = tid >> 6;
  const int wr = wid >> 1, wc = wid & 1;
  const int lg = lane >> 4, lr = lane & 15;

  // XCD-chunked decode (bijective: 768 = 8 XCD * 96): each XCD owns 16 m-blocks;
  // the 6 n-tiles of one m-block are dispatch-adjacent on one XCD -> L2 reuse of x.
  const int bid  = blockIdx.x;
  const int c    = bid >> 3;             // 0..95
  const int mblk = (bid & 7) * 16 + c / NBLK;
  const int nblk = c % NBLK;
  const int m0 = mblk * 128;             // block-level
  const int n0 = nblk * 128;             // block-level

  // ---- A staging: thread -> (row = tid>>1, 16-col half), linear LDS
  const int arow  = tid >> 1;
  const int ahalf = tid & 1;
  const float* abase = x + (size_t)(m0 + arow) * Tdim + ahalf * 16;
  const float* const aclamp = x + (size_t)Mtotal * Tdim - 16;  // last legal 16-f32 base
  const int awofs = arow * 32 + ahalf * 16;

  // ---- B staging: global_load_lds width 16, linear src & dest (m97 pattern)
  const int brow0 = wid * 32 + (lane >> 2);
  const __bf16* bsrc0 = Wb + (size_t)(n0 + brow0) * KP + (lane & 3) * 8;
  const __bf16* bsrc1 = bsrc0 + (size_t)16 * KP;

  // ---- fragment ds_read offsets (linear, wave offsets included HERE)
  int arofs[4], brofs[4];
  #pragma unroll
  for (int mi = 0; mi < 4; ++mi) arofs[mi] = (wr * 64 + mi * 16 + lr) * 32 + lg * 8;
  #pragma unroll
  for (int ni = 0; ni < 4; ++ni) brofs[ni] = (wc * 64 + ni * 16 + lr) * 32 + lg * 8;

  f32x4 acc[4][4];
  #pragma unroll
  for (int mi = 0; mi < 4; ++mi)
    #pragma unroll
    for (int ni = 0; ni < 4; ++ni) {
      f32x4 z; z[0] = 0.f; z[1] = 0.f; z[2] = 0.f; z[3] = 0.f;
      acc[mi][ni] = z;
    }

  // ---- prologue: stage tile 0 into buffer 0
  {
    __builtin_amdgcn_global_load_lds((gas_ptr)bsrc0, (las_ptr)&Bs[0][wid * 1024], 16, 0, 0);
    __builtin_amdgcn_global_load_lds((gas_ptr)bsrc1, (las_ptr)&Bs[0][wid * 1024 + 512], 16, 0, 0);
    const float* p = abase;
    if (p > aclamp) p = aclamp;
    f32x4 a0 = ((const f32x4*)p)[0];
    f32x4 a1 = ((const f32x4*)p)[1];
    f32x4 a2 = ((const f32x4*)p)[2];
    f32x4 a3 = ((const f32x4*)p)[3];
    bf16x8 v0, v1;
    #pragma unroll
    for (int j = 0; j < 4; ++j) {
      v0[j] = (__bf16)a0[j]; v0[j + 4] = (__bf16)a1[j];
      v1[j] = (__bf16)a2[j]; v1[j + 4] = (__bf16)a3[j];
    }
    *(bf16x8*)(&As[0][awofs])     = v0;
    *(bf16x8*)(&As[0][awofs + 8]) = v1;
  }
  __syncthreads();

  int buf = 0;
  for (int t = 0; t < NK; ++t) {
    const int nt = t + 1;
    f32x4 a0, a1, a2, a3;
    // ---- issue next tile's loads FIRST (latency overlaps compute below)
    if (nt < NK) {
      __builtin_amdgcn_global_load_lds((gas_ptr)(bsrc0 + nt * 32),
                                       (las_ptr)&Bs[buf ^ 1][wid * 1024], 16, 0, 0);
      __builtin_amdgcn_global_load_lds((gas_ptr)(bsrc1 + nt * 32),
                                       (las_ptr)&Bs[buf ^ 1][wid * 1024 + 512], 16, 0, 0);
      const float* p = abase + nt * 32;
      if (p > aclamp) p = aclamp;          // K-tail garbage hits zero-padded B cols
      a0 = ((const f32x4*)p)[0];
      a1 = ((const f32x4*)p)[1];
      a2 = ((const f32x4*)p)[2];
      a3 = ((const f32x4*)p)[3];
    }

    // ---- compute tile t from buf
    bf16x8 av[4], bv[4];
    #pragma unroll
    for (int mi = 0; mi < 4; ++mi) av[mi] = *(const bf16x8*)(&As[buf][arofs[mi]]);
    #pragma unroll
    for (int ni = 0; ni < 4; ++ni) bv[ni] = *(const bf16x8*)(&Bs[buf][brofs[ni]]);
    #pragma unroll
    for (int mi = 0; mi < 4; ++mi)
      #pragma unroll
      for (int ni = 0; ni < 4; ++ni)
        acc[mi][ni] = __builtin_amdgcn_mfma_f32_16x16x32_bf16(av[mi], bv[ni],
                                                              acc[mi][ni], 0, 0, 0);

    // ---- finish staging t+1 (cvt + ds_write; waitcnt for a0..a3 lands here)
    if (nt < NK) {
      bf16x8 v0, v1;
      #pragma unroll
      for (int j = 0; j < 4; ++j) {
        v0[j] = (__bf16)a0[j]; v0[j + 4] = (__bf16)a1[j];
        v1[j] = (__bf16)a2[j]; v1[j + 4] = (__bf16)a3[j];
      }
      *(bf16x8*)(&As[buf ^ 1][awofs])     = v0;
      *(bf16x8*)(&As[buf ^ 1][awofs + 8]) = v1;
    }

    __syncthreads();   // drains gl_lds (vmcnt) + ds_writes for t+1, releases buf
    buf ^= 1;
  }

  // ---- epilogue: C/D layout col = lane&15 (u), row = (lane>>4)*4 + reg (m)
  #pragma unroll
  for (int ni = 0; ni < 4; ++ni) {
    const int u = n0 + wc * 64 + ni * 16 + lr;
    if (u >= Tdim) continue;
    const float bias = beff[u];
    #pragma unroll
    for (int mi = 0; mi < 4; ++mi) {
      const int mb = m0 + wr * 64 + mi * 16 + lg * 4;
      #pragma unroll
      for (int j = 0; j < 4; ++j)
        out[(size_t)(mb + j) * Tdim + u] = acc[mi][ni][j] + bias;
    }
  }
}

extern "C" void kernel_launch(void* const* d_in, const int* in_sizes, int n_in,
                              void* d_out, int out_size, void* d_ws, size_t ws_size,
                              hipStream_t stream) {
  const float* x  = (const float*)d_in[0];
  const float* tw = (const float*)d_in[1];
  const float* tb = (const float*)d_in[2];
  const float* sw = (const float*)d_in[3];
  const float* sb = (const float*)d_in[4];
  float* out = (float*)d_out;

  __bf16* Wb  = (__bf16*)d_ws;
  float* beff = (float*)((char*)d_ws + (size_t)WROWS * KP * sizeof(__bf16));

  const int fold_total = WROWS * KP;
  fold_w_kernel<<<dim3((fold_total + 255) / 256), dim3(256), 0, stream>>>(
      tw, tb, sw, sb, Wb, beff);

  const int M = in_sizes[0] / Tdim;            // 16384
  dim3 grid((M / 128) * NBLK);                 // 768 blocks, 1D for XCD decode
  dlinear_gemm<<<grid, dim3(256), 0, stream>>>(x, Wb, beff, out, M);
}

// Round 6
// 48.884 us; speedup vs baseline: 1.2926x; 1.2926x over previous
//
#include <hip/hip_runtime.h>
#include <hip/hip_bf16.h>

// out[m,u] = sum_t x[m,t] * W_eff[u,t] + b_eff[u]      (m = 32*512 rows)
//   W_eff = Ws + (Wt - Ws) @ A   (A = causal window-mean, window 25)
// Round-6 structure: x-chunk (64 rows, bf16) resident in LDS; ONE barrier
// total; W streams global->reg with a named 2-stage pipeline; no main-loop
// barriers at all (removes the vmcnt(0) barrier-drain that capped rounds 4/5).

#define Tdim  720
#define KP    736      // padded K (23*32); Wb zero-filled for k>=720
#define WROWS 768      // padded u-rows of Wb (zero rows >=720)
#define NK    23
#define BM    64       // m-rows per block
#define APAD  744      // LDS row stride in elems (744*2B=1488B == 20 mod 32 dw -> 2-way)

using bf16x8 = __attribute__((ext_vector_type(8))) __bf16;
using f32x4  = __attribute__((ext_vector_type(4))) float;

__global__ void fold_w_kernel(const float* __restrict__ tw,
                              const float* __restrict__ tb,
                              const float* __restrict__ sw,
                              const float* __restrict__ sb,
                              __bf16* __restrict__ Wb,
                              float* __restrict__ beff) {
  int idx = blockIdx.x * 256 + threadIdx.x;
  if (idx >= WROWS * KP) return;
  int u = idx / KP;
  int i = idx - u * KP;
  float w = 0.0f;
  if (u < Tdim && i < Tdim) {
    const float* twr = tw + (size_t)u * Tdim;
    const float* swr = sw + (size_t)u * Tdim;
    int tend = (i + 25 < Tdim) ? (i + 25) : Tdim;
    float acc = 0.0f;
    if (i >= 24) {
      #pragma unroll 5
      for (int t = i; t < tend; ++t) acc += twr[t] - swr[t];
      acc *= 0.04f;
    } else {
      for (int t = i; t < tend; ++t) {
        float c = (t >= 24) ? 0.04f : 1.0f / (float)(t + 1);
        acc += (twr[t] - swr[t]) * c;
      }
    }
    w = swr[i] + acc;
  }
  Wb[idx] = (__bf16)w;
  if (i == 0 && u < Tdim) beff[u] = tb[u] + sb[u];
}

__global__ __launch_bounds__(512, 1)
void dlinear_gemm(const float* __restrict__ x,
                  const __bf16* __restrict__ Wb,
                  const float* __restrict__ beff,
                  float* __restrict__ out) {
  __shared__ __bf16 As[BM * APAD];   // 95232 B -> 1 block/CU

  const int tid  = threadIdx.x;
  const int lane = tid & 63;
  const int wid  = tid >> 6;          // 0..7
  const int lg = lane >> 4, lr = lane & 15;

  const int m0 = blockIdx.x * BM;
  const int u0 = wid * 96;            // wave owns 96 u-cols (768 = 8*96 padded)

  // ---- prologue: x[m0..m0+64) x [0..720) -> LDS bf16 (coalesced 32B/lane)
  #pragma unroll
  for (int c = 0; c < 12; ++c) {
    int idx = tid + 512 * c;          // 8-f32 chunk id; 90 chunks per row
    if (idx < BM * 90) {
      int row  = idx / 90;
      int col8 = idx - row * 90;
      const float* p = x + (size_t)(m0 + row) * Tdim + col8 * 8;
      f32x4 a0 = ((const f32x4*)p)[0];
      f32x4 a1 = ((const f32x4*)p)[1];
      bf16x8 v;
      #pragma unroll
      for (int j = 0; j < 4; ++j) { v[j] = (__bf16)a0[j]; v[j + 4] = (__bf16)a1[j]; }
      *(bf16x8*)(&As[row * APAD + col8 * 8]) = v;
    }
  }
  {  // zero the K-pad [720,736): garbage here could be NaN; W pad is exact 0
    int r = tid >> 3;
    int c = 720 + (tid & 7) * 2;
    As[r * APAD + c]     = (__bf16)0.0f;
    As[r * APAD + c + 1] = (__bf16)0.0f;
  }
  __syncthreads();                    // the ONLY barrier

  // ---- W stream pointers: frag ni -> row u0+ni*16+lr, bytes lg*16 within K-step
  const __bf16* wp[6];
  #pragma unroll
  for (int ni = 0; ni < 6; ++ni)
    wp[ni] = Wb + (size_t)(u0 + ni * 16 + lr) * KP + lg * 8;

  int arofs[4];
  #pragma unroll
  for (int mi = 0; mi < 4; ++mi) arofs[mi] = (mi * 16 + lr) * APAD + lg * 8;

  f32x4 acc[4][6];
  #pragma unroll
  for (int mi = 0; mi < 4; ++mi)
    #pragma unroll
    for (int ni = 0; ni < 6; ++ni) {
      f32x4 z; z[0] = 0.f; z[1] = 0.f; z[2] = 0.f; z[3] = 0.f;
      acc[mi][ni] = z;
    }

  // ---- K-loop: named 2-stage pipeline, zero barriers
  bf16x8 b0[6], b1[6];
  #pragma unroll
  for (int ni = 0; ni < 6; ++ni) b0[ni] = *(const bf16x8*)wp[ni];   // t=0

  for (int t = 0; t < NK - 1; t += 2) {   // t = 0,2,...,20
    // even step t: consume b0, prefetch t+1 into b1
    #pragma unroll
    for (int ni = 0; ni < 6; ++ni) b1[ni] = *(const bf16x8*)(wp[ni] + (t + 1) * 32);
    {
      bf16x8 av[4];
      #pragma unroll
      for (int mi = 0; mi < 4; ++mi) av[mi] = *(const bf16x8*)(&As[arofs[mi] + t * 32]);
      #pragma unroll
      for (int mi = 0; mi < 4; ++mi)
        #pragma unroll
        for (int ni = 0; ni < 6; ++ni)
          acc[mi][ni] = __builtin_amdgcn_mfma_f32_16x16x32_bf16(av[mi], b0[ni],
                                                                acc[mi][ni], 0, 0, 0);
    }
    // odd step t+1: consume b1, prefetch t+2 into b0 (t+2 <= 22 always valid)
    #pragma unroll
    for (int ni = 0; ni < 6; ++ni) b0[ni] = *(const bf16x8*)(wp[ni] + (t + 2) * 32);
    {
      bf16x8 av[4];
      #pragma unroll
      for (int mi = 0; mi < 4; ++mi) av[mi] = *(const bf16x8*)(&As[arofs[mi] + (t + 1) * 32]);
      #pragma unroll
      for (int mi = 0; mi < 4; ++mi)
        #pragma unroll
        for (int ni = 0; ni < 6; ++ni)
          acc[mi][ni] = __builtin_amdgcn_mfma_f32_16x16x32_bf16(av[mi], b1[ni],
                                                                acc[mi][ni], 0, 0, 0);
    }
  }
  {  // tail t = 22 consumes b0
    bf16x8 av[4];
    #pragma unroll
    for (int mi = 0; mi < 4; ++mi) av[mi] = *(const bf16x8*)(&As[arofs[mi] + 22 * 32]);
    #pragma unroll
    for (int mi = 0; mi < 4; ++mi)
      #pragma unroll
      for (int ni = 0; ni < 6; ++ni)
        acc[mi][ni] = __builtin_amdgcn_mfma_f32_16x16x32_bf16(av[mi], b0[ni],
                                                              acc[mi][ni], 0, 0, 0);
  }

  // ---- epilogue: C/D layout col = lr -> u, row = lg*4 + j -> m
  #pragma unroll
  for (int ni = 0; ni < 6; ++ni) {
    const int u = u0 + ni * 16 + lr;
    if (u >= Tdim) continue;
    const float bias = beff[u];
    #pragma unroll
    for (int mi = 0; mi < 4; ++mi) {
      const int mb = m0 + mi * 16 + lg * 4;
      #pragma unroll
      for (int j = 0; j < 4; ++j)
        out[(size_t)(mb + j) * Tdim + u] = acc[mi][ni][j] + bias;
    }
  }
}

extern "C" void kernel_launch(void* const* d_in, const int* in_sizes, int n_in,
                              void* d_out, int out_size, void* d_ws, size_t ws_size,
                              hipStream_t stream) {
  const float* x  = (const float*)d_in[0];
  const float* tw = (const float*)d_in[1];
  const float* tb = (const float*)d_in[2];
  const float* sw = (const float*)d_in[3];
  const float* sb = (const float*)d_in[4];
  float* out = (float*)d_out;

  __bf16* Wb  = (__bf16*)d_ws;
  float* beff = (float*)((char*)d_ws + (size_t)WROWS * KP * sizeof(__bf16));

  const int fold_total = WROWS * KP;
  fold_w_kernel<<<dim3((fold_total + 255) / 256), dim3(256), 0, stream>>>(
      tw, tb, sw, sb, Wb, beff);

  const int M = in_sizes[0] / Tdim;            // 16384
  dim3 grid(M / BM);                           // 256 blocks, 1 per CU
  dlinear_gemm<<<grid, dim3(512), 0, stream>>>(x, Wb, beff, out);
}